// Round 1
// baseline (26.003 us; speedup 1.0000x reference)
//
#include <hip/hip_runtime.h>
#include <hip/hip_bf16.h>

// EmbeddedDropout: out[t, :] = scale(words[t]) * weight[words[t], :]
// scale(v) = (mask_u[v] < 0.9f) ? (1.0f/0.9f) : 0.0f   (inverted dropout, p=0.1)
//
// Shapes: weight (V=50257, D=1024) f32, mask_u (V,) f32, words (B*S=16384,) int32
// out: (16384, 1024) f32.
//
// Memory-bound gather: 1 block per token row, 256 threads x float4 = 1024 f32.

__global__ __launch_bounds__(256) void embed_dropout_kernel(
    const float* __restrict__ weight,
    const float* __restrict__ mask_u,
    const int* __restrict__ words,
    float* __restrict__ out,
    int D,            // row length in floats (1024)
    int n_tokens)     // number of token rows (16384)
{
    const int row = blockIdx.x;
    if (row >= n_tokens) return;

    const int idx = words[row];
    const float keep = 0.9f;
    const float scale = (mask_u[idx] < keep) ? (1.0f / keep) : 0.0f;

    const float4* __restrict__ src =
        reinterpret_cast<const float4*>(weight + (size_t)idx * (size_t)D);
    float4* __restrict__ dst =
        reinterpret_cast<float4*>(out + (size_t)row * (size_t)D);

    const int nvec = D >> 2;  // float4 count per row
    for (int i = threadIdx.x; i < nvec; i += blockDim.x) {
        float4 v = src[i];
        v.x *= scale; v.y *= scale; v.z *= scale; v.w *= scale;
        dst[i] = v;
    }
}

extern "C" void kernel_launch(void* const* d_in, const int* in_sizes, int n_in,
                              void* d_out, int out_size, void* d_ws, size_t ws_size,
                              hipStream_t stream) {
    const float* weight = (const float*)d_in[0];
    const float* mask_u = (const float*)d_in[1];
    const int*   words  = (const int*)d_in[2];
    float* out = (float*)d_out;

    const int V = in_sizes[1];              // mask_u has V elements
    const int D = in_sizes[0] / V;          // 1024
    const int n_tokens = in_sizes[2];       // 16384
    (void)out_size; (void)d_ws; (void)ws_size; (void)n_in;

    dim3 grid(n_tokens);
    dim3 block(256);
    embed_dropout_kernel<<<grid, block, 0, stream>>>(
        weight, mask_u, words, out, D, n_tokens);
}